// Round 16
// baseline (220.916 us; speedup 1.0000x reference)
//
#include <hip/hip_runtime.h>
#include <hip/hip_bf16.h>

typedef __attribute__((ext_vector_type(8))) short bf8_t;          // 8 x bf16
typedef __attribute__((ext_vector_type(4))) float f32x4;
typedef __attribute__((ext_vector_type(4))) unsigned short u16x4;
typedef __attribute__((ext_vector_type(2))) unsigned int u32x2;
typedef unsigned long long ull;

#define DEVI static __device__ __forceinline__

DEVI unsigned short f2bf(float f) {
  union { __hip_bfloat16 h; unsigned short u; } cv;
  cv.h = __float2bfloat16(f);
  return cv.u;
}
DEVI float bf2f(unsigned short u) {
  union { __hip_bfloat16 h; unsigned short u; } cv;
  cv.u = u;
  return __bfloat162float(cv.h);
}
DEVI unsigned int pack2(float lo, float hi) {
  return (unsigned int)f2bf(lo) | ((unsigned int)f2bf(hi) << 16);
}

// ---------------- prep_w: fragment-swizzle wq/wk/wv (bf16) ----------------
__global__ __launch_bounds__(256) void prep_w_kernel(
    const float* __restrict__ wq, const float* __restrict__ wk, const float* __restrict__ wv,
    unsigned short* __restrict__ wqf, unsigned short* __restrict__ wkf,
    unsigned short* __restrict__ wvf)
{
  const int wsel = blockIdx.x >> 8;
  const int i = (blockIdx.x & 255) * 256 + threadIdx.x;   // f32x4 index
  const float* s = (wsel == 0) ? wq : (wsel == 1) ? wk : wv;
  unsigned short* d = (wsel == 0) ? wqf : (wsel == 1) ? wkf : wvf;
  float4 v = reinterpret_cast<const float4*>(s)[i];
  u16x4 o;
  o[0] = f2bf(v.x); o[1] = f2bf(v.y); o[2] = f2bf(v.z); o[3] = f2bf(v.w);
  const int i4 = i * 4;
  const int n = i4 >> 9, k0 = i4 & 511;
  const int h = n >> 6, nr = n & 63;
  const long long off = (long long)h * 32768 + (k0 >> 5) * 2048 + (nr >> 4) * 512 +
                        ((((k0 >> 3) & 3) << 4) + (nr & 15)) * 8 + (k0 & 7);
  *reinterpret_cast<u16x4*>(d + off) = o;
}

// ---------------- merged: qkv GEMM (bx<384) + maskpack (384..2431) + wo cvt (2432..2687) ----------------
__global__ __launch_bounds__(256) void mask_qkv_kernel(
    const float* __restrict__ mask, const float* __restrict__ x,
    const float* __restrict__ wo,
    const unsigned short* __restrict__ wqf, const unsigned short* __restrict__ wkf,
    const unsigned short* __restrict__ wvf,
    const float* __restrict__ bq, const float* __restrict__ bk, const float* __restrict__ bv,
    ull* __restrict__ bits,
    unsigned short* __restrict__ qs, unsigned short* __restrict__ ks,
    unsigned short* __restrict__ vs,
    unsigned short* __restrict__ qns, unsigned short* __restrict__ kns,
    unsigned short* __restrict__ wo_bf)
{
  __shared__ unsigned short xfrag[32768];   // 64 KB (qkv branch only)
  __shared__ unsigned short stage[4096];
  __shared__ float irn_lds[64];
  const int bx = blockIdx.x;
  const int w = threadIdx.x >> 6, L = threadIdx.x & 63, c = L & 15, g = L >> 4;
  const int t = threadIdx.x;

  if (bx >= 2432) {
    const int i = (bx - 2432) * 256 + t;
    float4 v = reinterpret_cast<const float4*>(wo)[i];
    u16x4 o;
    o[0] = f2bf(v.x); o[1] = f2bf(v.y); o[2] = f2bf(v.z); o[3] = f2bf(v.w);
    reinterpret_cast<u16x4*>(wo_bf)[i] = o;
    return;
  }
  if (bx >= 384) {
    const long long row = (long long)(bx - 384) * 4 + w;
    const float* mp = mask + row * 1024 + 4 * L;
    ull* bout = bits + row * 16;
#pragma unroll
    for (int p = 0; p < 4; ++p) {
      float4 v = *reinterpret_cast<const float4*>(mp + 256 * p);
      ull b0 = __ballot(v.x != 0.f);
      ull b1 = __ballot(v.y != 0.f);
      ull b2 = __ballot(v.z != 0.f);
      ull b3 = __ballot(v.w != 0.f);
      if (L == 0) {
        bout[4 * p + 0] = b0; bout[4 * p + 1] = b1;
        bout[4 * p + 2] = b2; bout[4 * p + 3] = b3;
      }
    }
    return;
  }

  // ---- QKV GEMM ----
  const int m0 = (bx & 127) * 64;
  const int p = bx >> 7;
  const unsigned short* Wf = (p == 0) ? wqf : (p == 1) ? wkf : wvf;
  const float* bias = (p == 0) ? bq : (p == 1) ? bk : bv;

  const float4* xsrc = reinterpret_cast<const float4*>(x + (long long)m0 * 512);
#pragma unroll 4
  for (int pass = 0; pass < 32; ++pass) {
    const int flat = pass * 1024 + t * 4;
    const int row = flat >> 9, k0 = flat & 511;
    float4 v = xsrc[pass * 256 + t];
    u16x4 o;
    o[0] = f2bf(v.x); o[1] = f2bf(v.y); o[2] = f2bf(v.z); o[3] = f2bf(v.w);
    const int off = (row >> 4) * 8192 + (k0 >> 5) * 512 +
                    ((((k0 >> 3) & 3) << 4) + (row & 15)) * 8 + (k0 & 7);
    *reinterpret_cast<u16x4*>(xfrag + off) = o;
  }
  __syncthreads();

  const int b = m0 >> 10;
  const int mloc = m0 & 1023;

  for (int h = 0; h < 8; ++h) {
    f32x4 acc0 = {0.f, 0.f, 0.f, 0.f}, acc1 = acc0, acc2 = acc0, acc3 = acc0;
    const unsigned short* xw = xfrag + w * 8192 + L * 8;
    const unsigned short* wb = Wf + (long long)h * 32768 + L * 8;
#pragma unroll 4
    for (int kk = 0; kk < 16; ++kk) {
      bf8_t a  = *reinterpret_cast<const bf8_t*>(xw + kk * 512);
      const unsigned short* wk8 = wb + kk * 2048;
      bf8_t b0 = *reinterpret_cast<const bf8_t*>(wk8);
      bf8_t b1 = *reinterpret_cast<const bf8_t*>(wk8 + 512);
      bf8_t b2 = *reinterpret_cast<const bf8_t*>(wk8 + 1024);
      bf8_t b3 = *reinterpret_cast<const bf8_t*>(wk8 + 1536);
      acc0 = __builtin_amdgcn_mfma_f32_16x16x32_bf16(a, b0, acc0, 0, 0, 0);
      acc1 = __builtin_amdgcn_mfma_f32_16x16x32_bf16(a, b1, acc1, 0, 0, 0);
      acc2 = __builtin_amdgcn_mfma_f32_16x16x32_bf16(a, b2, acc2, 0, 0, 0);
      acc3 = __builtin_amdgcn_mfma_f32_16x16x32_bf16(a, b3, acc3, 0, 0, 0);
    }
    f32x4 accs[4] = {acc0, acc1, acc2, acc3};
    unsigned short ub[4][4];
    float nacc[4] = {0.f, 0.f, 0.f, 0.f};
#pragma unroll
    for (int tt = 0; tt < 4; ++tt) {
      float bvt = bias[h * 64 + 16 * tt + c];
#pragma unroll
      for (int r = 0; r < 4; ++r) {
        ub[tt][r] = f2bf(accs[tt][r] + bvt);
        float vv = bf2f(ub[tt][r]);
        nacc[r] += vv * vv;
      }
    }
    if (p == 2) {
      const long long vbase = (long long)(b * 8 + h) * 65536 +
                              (long long)((mloc >> 5) + (w >> 1)) * 2048 +
                              (16 * g + c) * 8 + 4 * (w & 1);
#pragma unroll
      for (int tt = 0; tt < 4; ++tt) {
        u16x4 o;
#pragma unroll
        for (int r = 0; r < 4; ++r) o[r] = ub[tt][r];
        *reinterpret_cast<u16x4*>(vs + vbase + tt * 512) = o;
      }
    } else {
      float irn[4];
#pragma unroll
      for (int r = 0; r < 4; ++r) {
#pragma unroll
        for (int off = 1; off < 16; off <<= 1) nacc[r] += __shfl_xor(nacc[r], off, 64);
        irn[r] = rsqrtf(nacc[r]);
      }
      if (c == 0) {
#pragma unroll
        for (int r = 0; r < 4; ++r) irn_lds[16 * w + 4 * g + r] = irn[r];
      }
#pragma unroll
      for (int tt = 0; tt < 4; ++tt) {
        const int half = tt >> 1;
        const int lpart = 16 * ((2 * tt + (c >> 3)) & 3);
#pragma unroll
        for (int r = 0; r < 4; ++r)
          stage[w * 1024 + half * 512 + (lpart + 4 * g + r) * 8 + (c & 7)] = ub[tt][r];
      }
      __syncthreads();
      unsigned short* dst = (p == 0) ? qs : ks;
      unsigned short* nrm = (p == 0) ? qns : kns;
      const long long qsb0 = (long long)(b * 8 + h) * 65536 + (long long)(mloc >> 4) * 1024;
      const long long nsb0 = (long long)b * 524288 + (long long)(mloc >> 4) * 8192 +
                             (long long)(2 * h) * 512;
#pragma unroll
      for (int pass = 0; pass < 2; ++pass) {
        const int Wd = t + 256 * pass;
        const int tile = Wd >> 7, lane = Wd & 63;
        const int il = tile * 16 + (Wd & 15);
        bf8_t v = *reinterpret_cast<const bf8_t*>(stage + Wd * 8);
        float f = irn_lds[il];
        *reinterpret_cast<bf8_t*>(dst + qsb0 + (long long)Wd * 8) = v;
        bf8_t nv;
#pragma unroll
        for (int e = 0; e < 8; ++e)
          nv[e] = (short)f2bf(bf2f((unsigned short)v[e]) * f);
        *reinterpret_cast<bf8_t*>(nrm + nsb0 + (long long)tile * 8192 +
                                  (long long)((Wd >> 6) & 1) * 512 + (long long)lane * 8) = nv;
      }
      __syncthreads();
    }
  }
}

// ---------------- merged: attn (by<64) + loss (by 64..71) ----------------
// Barrier-drain-aware schedule: no VMEM in flight at B1 (V loads issued after B1,
// covered by scale+pack VALU); attn NT stores deferred past B2 to kernel end
// (P rows snapshotted to regs before the O overwrite) so no barrier drains them.
__global__ __launch_bounds__(512, 4) void attn_loss_kernel(
    const unsigned short* __restrict__ qs, const unsigned short* __restrict__ ks,
    const ull* __restrict__ bits, const unsigned short* __restrict__ vs,
    const unsigned short* __restrict__ qns, const unsigned short* __restrict__ kns,
    float* __restrict__ attn_out, unsigned short* __restrict__ inter,
    float* __restrict__ partials)
{
  __shared__ unsigned int PO_lds[8 * 1088];   // 34.8 KB union P/O
  __shared__ float redM[8][16], redS[8][16];
  __shared__ float redN[8][16], redD[8][16], redP[8][16];
  const int w = threadIdx.x >> 6, L = threadIdx.x & 63, c = L & 15, g = L >> 4;

  if (blockIdx.y < 64) {
    const int bh = blockIdx.x;                 // fast dim -> XCD locality
    const int i0 = blockIdx.y * 16;
    const int b = bh >> 3, h = bh & 7;
    const int j0 = 128 * w;
    const long long bho = (long long)bh * 65536;

    const unsigned short* qp = qs + bho + (i0 >> 4) * 1024 + L * 8;
    bf8_t qf0 = *reinterpret_cast<const bf8_t*>(qp);
    bf8_t qf1 = *reinterpret_cast<const bf8_t*>(qp + 512);

    const ull* bp = bits + ((long long)b * 1024 + i0 + c) * 16 + 4 * (w >> 1);
    ull mw[4];
    {
      ulonglong2 m01 = *reinterpret_cast<const ulonglong2*>(bp);
      ulonglong2 m23 = *reinterpret_cast<const ulonglong2*>(bp + 2);
      mw[0] = m01.x; mw[1] = m01.y; mw[2] = m23.x; mw[3] = m23.y;
    }
    const int bitbase = 32 * (w & 1) + g;

    f32x4 sc[8];
    const unsigned short* kp = ks + bho + (long long)(8 * w) * 1024 + L * 8;
#pragma unroll
    for (int jt = 0; jt < 8; ++jt) {
      const unsigned short* kt = kp + jt * 1024;
      f32x4 acc = {0.f, 0.f, 0.f, 0.f};
      acc = __builtin_amdgcn_mfma_f32_16x16x32_bf16(*reinterpret_cast<const bf8_t*>(kt), qf0, acc, 0, 0, 0);
      acc = __builtin_amdgcn_mfma_f32_16x16x32_bf16(*reinterpret_cast<const bf8_t*>(kt + 512), qf1, acc, 0, 0, 0);
      sc[jt] = acc;
    }

    float rmax = -1e30f;
#pragma unroll
    for (int jt = 0; jt < 8; ++jt) {
#pragma unroll
      for (int r = 0; r < 4; ++r) {
        float lg = ((mw[r] >> (bitbase + 4 * jt)) & 1ull) ? sc[jt][r] * 0.125f
                                                          : -2.8782313662425572f;
        sc[jt][r] = lg;
        rmax = fmaxf(rmax, lg);
      }
    }
    rmax = fmaxf(rmax, __shfl_xor(rmax, 16, 64));
    rmax = fmaxf(rmax, __shfl_xor(rmax, 32, 64));
    float rsum = 0.f;
#pragma unroll
    for (int jt = 0; jt < 8; ++jt) {
#pragma unroll
      for (int r = 0; r < 4; ++r) {
        float e = __expf(sc[jt][r] - rmax);
        sc[jt][r] = e;
        rsum += e;
      }
    }
    rsum += __shfl_xor(rsum, 16, 64);
    rsum += __shfl_xor(rsum, 32, 64);
    if (L < 16) { redM[w][L] = rmax; redS[w][L] = rsum; }
    __syncthreads();  // B1 — no VMEM outstanding here

    // issue V loads batch 1 now; scale + pack VALU below covers their latency
    const unsigned short* vbase = vs + bho + (long long)(16 * w) * 512 + L * 8;
    bf8_t vpre[8];
#pragma unroll
    for (int vv = 0; vv < 8; ++vv) vpre[vv] = *reinterpret_cast<const bf8_t*>(vbase + vv * 512);

    float M = redM[0][c];
#pragma unroll
    for (int ww = 1; ww < 8; ++ww) M = fmaxf(M, redM[ww][c]);
    float den = 0.f;
#pragma unroll
    for (int ww = 0; ww < 8; ++ww) den += redS[ww][c] * __expf(redM[ww][c] - M);
    const float scale = __expf(rmax - M) / den;

    // scale + pack; stage P rows into my LDS plane
    unsigned int* Pw = PO_lds + w * 1088;
    unsigned int pk[16];
#pragma unroll
    for (int jt = 0; jt < 8; ++jt) {
      f32x4 pv;
#pragma unroll
      for (int r = 0; r < 4; ++r) pv[r] = sc[jt][r] * scale;
      pk[2 * jt]     = pack2(pv[0], pv[1]);
      pk[2 * jt + 1] = pack2(pv[2], pv[3]);
      u32x2 pw2;
      pw2[0] = pk[2 * jt]; pw2[1] = pk[2 * jt + 1];
      *reinterpret_cast<u32x2*>(Pw + c * 68 + 8 * jt + 2 * g) = pw2;
    }

    // issue V loads batch 2 before the MFMA burst
    bf8_t vtail[8];
#pragma unroll
    for (int vv = 0; vv < 8; ++vv)
      vtail[vv] = *reinterpret_cast<const bf8_t*>(vbase + (8 + vv) * 512);

    // PV: MFMA burst from registers
    f32x4 oacc[4] = {{0.f,0.f,0.f,0.f},{0.f,0.f,0.f,0.f},{0.f,0.f,0.f,0.f},{0.f,0.f,0.f,0.f}};
#pragma unroll
    for (int m = 0; m < 4; ++m) {
      union { unsigned int u[4]; bf8_t v; } af;
#pragma unroll
      for (int q = 0; q < 4; ++q) af.u[q] = pk[4 * m + q];
#pragma unroll
      for (int tt = 0; tt < 4; ++tt) {
        bf8_t vb = (m < 2) ? vpre[4 * m + tt] : vtail[4 * (m - 2) + tt];
        oacc[tt] = __builtin_amdgcn_mfma_f32_16x16x32_bf16(af.v, vb, oacc[tt], 0, 0, 0);
      }
    }

    // snapshot my P rows to registers (LDS reads, ordered before the O overwrite)
    u32x2 prow[8];
    const int lj = L & 31, lh = L >> 5;
#pragma unroll
    for (int ii = 0; ii < 8; ++ii)
      prow[ii] = *reinterpret_cast<const u32x2*>(Pw + (2 * ii + lh) * 68 + 2 * lj);

    // O partials into my plane (overwrites P)
    {
      float* Ow = reinterpret_cast<float*>(PO_lds + w * 1088);
#pragma unroll
      for (int tt = 0; tt < 4; ++tt)
#pragma unroll
        for (int r = 0; r < 4; ++r)
          Ow[(4 * g + r) * 67 + 16 * tt + c] = oacc[tt][r];
    }
    __syncthreads();  // B2 — no VMEM stores outstanding (attn stores deferred)

    {
      const int d = threadIdx.x & 63, rw = threadIdx.x >> 6;
#pragma unroll
      for (int ii = 0; ii < 2; ++ii) {
        const int i = rw + 8 * ii;
        float s = 0.f;
#pragma unroll
        for (int ww = 0; ww < 8; ++ww)
          s += reinterpret_cast<const float*>(PO_lds + ww * 1088)[i * 67 + d];
        inter[((long long)b * 1024 + i0 + i) * 512 + h * 64 + d] = f2bf(s);
      }
    }

    // deferred coalesced attn stores (no barrier after -> no drain stall)
    {
      float* aobase = attn_out + (long long)bh * 1048576 + (long long)i0 * 1024 + j0;
#pragma unroll
      for (int ii = 0; ii < 8; ++ii) {
        const int row = 2 * ii + lh;
        f32x4 o4;
        o4[0] = bf2f((unsigned short)(prow[ii][0] & 0xffff));
        o4[1] = bf2f((unsigned short)(prow[ii][0] >> 16));
        o4[2] = bf2f((unsigned short)(prow[ii][1] & 0xffff));
        o4[3] = bf2f((unsigned short)(prow[ii][1] >> 16));
        __builtin_nontemporal_store(o4,
            reinterpret_cast<f32x4*>(aobase + (long long)row * 1024 + 4 * lj));
      }
    }
  } else {
    const int i0 = blockIdx.x * 16;
    const int b = blockIdx.y - 64;
    const long long rowbase = (long long)b * 1024;

    f32x4 acc[8];
#pragma unroll
    for (int jt = 0; jt < 8; ++jt) acc[jt] = f32x4{0.f, 0.f, 0.f, 0.f};
    const unsigned short* qp = qns + (long long)b * 524288 + (long long)(i0 >> 4) * 8192 + L * 8;
    const unsigned short* kp = kns + (long long)b * 524288 + (long long)(8 * w) * 8192 + L * 8;
#pragma unroll 2
    for (int kc = 0; kc < 16; ++kc) {
      bf8_t a = *reinterpret_cast<const bf8_t*>(qp + kc * 512);
#pragma unroll
      for (int jt = 0; jt < 8; ++jt) {
        bf8_t bb = *reinterpret_cast<const bf8_t*>(kp + jt * 8192 + kc * 512);
        acc[jt] = __builtin_amdgcn_mfma_f32_16x16x32_bf16(a, bb, acc[jt], 0, 0, 0);
      }
    }

    const int e = c & 3, csh = c >> 2, half = (w & 1) * 32;
    ull w64[4];
#pragma unroll
    for (int r = 0; r < 4; ++r)
      w64[r] = bits[(rowbase + i0 + 4 * g + r) * 16 + 4 * (w >> 1) + e];

    float num[4] = {0.f, 0.f, 0.f, 0.f}, den[4] = {0.f, 0.f, 0.f, 0.f}, pcv[4];
#pragma unroll
    for (int r = 0; r < 4; ++r)
      pcv[r] = (c < 4) ? (float)__popcll((w64[r] >> half) & 0xFFFFFFFFull) : 0.f;
#pragma unroll
    for (int jt = 0; jt < 8; ++jt) {
#pragma unroll
      for (int r = 0; r < 4; ++r) {
        float ee = __expf(acc[jt][r] * 1.25f);
        den[r] += ee;
        num[r] += ((w64[r] >> (half + 4 * jt + csh)) & 1ull) ? ee : 0.f;
      }
    }
#pragma unroll
    for (int r = 0; r < 4; ++r) {
#pragma unroll
      for (int off = 1; off < 16; off <<= 1) {
        num[r] += __shfl_xor(num[r], off, 64);
        den[r] += __shfl_xor(den[r], off, 64);
        pcv[r] += __shfl_xor(pcv[r], off, 64);
      }
    }
    if (c == 0) {
#pragma unroll
      for (int r = 0; r < 4; ++r) {
        redN[w][4 * g + r] = num[r]; redD[w][4 * g + r] = den[r]; redP[w][4 * g + r] = pcv[r];
      }
    }
    __syncthreads();
    if (w == 0) {
      float cl = 0.f, rg = 0.f;
      if (L < 16) {
        float nm = 0.f, dn = 0.f, pc = 0.f;
#pragma unroll
        for (int ww = 0; ww < 8; ++ww) { nm += redN[ww][L]; dn += redD[ww][L]; pc += redP[ww][L]; }
        cl = __logf(dn) - __logf(nm);
        rg = pc - 1.0f;
      }
#pragma unroll
      for (int off = 1; off < 64; off <<= 1) { cl += __shfl_xor(cl, off, 64); rg += __shfl_xor(rg, off, 64); }
      if (L == 0)
        partials[b * 64 + blockIdx.x] = cl * (1.0f / 8192.0f) + rg * (float)(0.3 / 8380416.0);
    }
  }
}

// ---------------- out-proj GEMM + folded loss reduction (block x==128) ----------------
__global__ __launch_bounds__(256) void outproj_gemm_kernel(
    const unsigned short* __restrict__ A, const unsigned short* __restrict__ W,
    const float* __restrict__ bias, float* __restrict__ out_f32,
    const float* __restrict__ partials, float* __restrict__ loss_out)
{
  if (blockIdx.x == 128) {
    if (blockIdx.y == 0) {
      int t = threadIdx.x;
      float s = partials[t] + partials[t + 256];
#pragma unroll
      for (int off = 1; off < 64; off <<= 1) s += __shfl_xor(s, off, 64);
      __shared__ float red[4];
      if ((t & 63) == 0) red[t >> 6] = s;
      __syncthreads();
      if (t == 0) loss_out[0] = red[0] + red[1] + red[2] + red[3];
    }
    return;
  }
  const int m0 = blockIdx.x * 64;
  const int n0 = blockIdx.y * 64;
  const int w = threadIdx.x >> 6, L = threadIdx.x & 63, c = L & 15, g = L >> 4;
  const unsigned short* arow = A + (long long)(m0 + 16 * w + c) * 512 + 8 * g;
  const unsigned short* wrow = W + (long long)(n0 + c) * 512 + 8 * g;
  f32x4 acc0 = {0.f, 0.f, 0.f, 0.f}, acc1 = acc0, acc2 = acc0, acc3 = acc0;
#pragma unroll 4
  for (int kk = 0; kk < 16; ++kk) {
    bf8_t a  = *reinterpret_cast<const bf8_t*>(arow + 32 * kk);
    bf8_t b0 = *reinterpret_cast<const bf8_t*>(wrow + 32 * kk);
    bf8_t b1 = *reinterpret_cast<const bf8_t*>(wrow + 16 * 512 + 32 * kk);
    bf8_t b2 = *reinterpret_cast<const bf8_t*>(wrow + 32 * 512 + 32 * kk);
    bf8_t b3 = *reinterpret_cast<const bf8_t*>(wrow + 48 * 512 + 32 * kk);
    acc0 = __builtin_amdgcn_mfma_f32_16x16x32_bf16(a, b0, acc0, 0, 0, 0);
    acc1 = __builtin_amdgcn_mfma_f32_16x16x32_bf16(a, b1, acc1, 0, 0, 0);
    acc2 = __builtin_amdgcn_mfma_f32_16x16x32_bf16(a, b2, acc2, 0, 0, 0);
    acc3 = __builtin_amdgcn_mfma_f32_16x16x32_bf16(a, b3, acc3, 0, 0, 0);
  }
  f32x4 accs[4] = {acc0, acc1, acc2, acc3};
#pragma unroll
  for (int tt = 0; tt < 4; ++tt) {
    int n = n0 + 16 * tt + c;
    float bv = bias[n];
#pragma unroll
    for (int r = 0; r < 4; ++r)
      out_f32[(long long)(m0 + 16 * w + 4 * g + r) * 512 + n] = accs[tt][r] + bv;
  }
}

extern "C" void kernel_launch(void* const* d_in, const int* in_sizes, int n_in,
                              void* d_out, int out_size, void* d_ws, size_t ws_size,
                              hipStream_t stream)
{
  const float* x    = (const float*)d_in[0];
  const float* mask = (const float*)d_in[1];
  const float* wq = (const float*)d_in[2]; const float* bq = (const float*)d_in[3];
  const float* wk = (const float*)d_in[4]; const float* bk = (const float*)d_in[5];
  const float* wv = (const float*)d_in[6]; const float* bv = (const float*)d_in[7];
  const float* wo = (const float*)d_in[8]; const float* bo = (const float*)d_in[9];

  unsigned short* inter = (unsigned short*)d_ws;
  unsigned short* qs    = inter + 4194304;
  unsigned short* ks    = qs + 4194304;
  unsigned short* vsb   = ks + 4194304;
  unsigned short* qns   = vsb + 4194304;
  unsigned short* kns   = qns + 4194304;
  unsigned short* wqf   = kns + 4194304;       // 262144 each
  unsigned short* wkf   = wqf + 262144;
  unsigned short* wvf   = wkf + 262144;
  unsigned short* wo_bf = wvf + 262144;
  ull* bits    = (ull*)(wo_bf + 262144);        // 1 MB
  float* parts = (float*)(bits + 131072);       // 512 f32

  float* out_f  = (float*)d_out;
  float* attn_o = out_f + 4194304;
  float* loss_o = attn_o + 67108864;

  prep_w_kernel<<<768, 256, 0, stream>>>(wq, wk, wv, wqf, wkf, wvf);

  mask_qkv_kernel<<<2688, 256, 0, stream>>>(
      mask, x, wo, wqf, wkf, wvf, bq, bk, bv,
      bits, qs, ks, vsb, qns, kns, wo_bf);

  attn_loss_kernel<<<dim3(64, 72), 512, 0, stream>>>(
      qs, ks, bits, vsb, qns, kns, attn_o, inter, parts);

  outproj_gemm_kernel<<<dim3(129, 8), 256, 0, stream>>>(
      inter, wo_bf, bo, out_f, parts, loss_o);
}

// Round 17
// 211.844 us; speedup vs baseline: 1.0428x; 1.0428x over previous
//
#include <hip/hip_runtime.h>
#include <hip/hip_bf16.h>

typedef __attribute__((ext_vector_type(8))) short bf8_t;          // 8 x bf16
typedef __attribute__((ext_vector_type(4))) float f32x4;
typedef __attribute__((ext_vector_type(4))) unsigned short u16x4;
typedef __attribute__((ext_vector_type(2))) unsigned int u32x2;
typedef unsigned long long ull;

#define DEVI static __device__ __forceinline__

DEVI unsigned short f2bf(float f) {
  union { __hip_bfloat16 h; unsigned short u; } cv;
  cv.h = __float2bfloat16(f);
  return cv.u;
}
DEVI float bf2f(unsigned short u) {
  union { __hip_bfloat16 h; unsigned short u; } cv;
  cv.u = u;
  return __bfloat162float(cv.h);
}
DEVI unsigned int pack2(float lo, float hi) {
  return (unsigned int)f2bf(lo) | ((unsigned int)f2bf(hi) << 16);
}

// ---------------- prep_w: fragment-swizzle wq/wk/wv (bf16) ----------------
__global__ __launch_bounds__(256) void prep_w_kernel(
    const float* __restrict__ wq, const float* __restrict__ wk, const float* __restrict__ wv,
    unsigned short* __restrict__ wqf, unsigned short* __restrict__ wkf,
    unsigned short* __restrict__ wvf)
{
  const int wsel = blockIdx.x >> 8;
  const int i = (blockIdx.x & 255) * 256 + threadIdx.x;   // f32x4 index
  const float* s = (wsel == 0) ? wq : (wsel == 1) ? wk : wv;
  unsigned short* d = (wsel == 0) ? wqf : (wsel == 1) ? wkf : wvf;
  float4 v = reinterpret_cast<const float4*>(s)[i];
  u16x4 o;
  o[0] = f2bf(v.x); o[1] = f2bf(v.y); o[2] = f2bf(v.z); o[3] = f2bf(v.w);
  const int i4 = i * 4;
  const int n = i4 >> 9, k0 = i4 & 511;
  const int h = n >> 6, nr = n & 63;
  const long long off = (long long)h * 32768 + (k0 >> 5) * 2048 + (nr >> 4) * 512 +
                        ((((k0 >> 3) & 3) << 4) + (nr & 15)) * 8 + (k0 & 7);
  *reinterpret_cast<u16x4*>(d + off) = o;
}

// ---------------- merged: qkv GEMM (bx<384) + maskpack (384..2431) + wo cvt (2432..2687) ----------------
__global__ __launch_bounds__(256) void mask_qkv_kernel(
    const float* __restrict__ mask, const float* __restrict__ x,
    const float* __restrict__ wo,
    const unsigned short* __restrict__ wqf, const unsigned short* __restrict__ wkf,
    const unsigned short* __restrict__ wvf,
    const float* __restrict__ bq, const float* __restrict__ bk, const float* __restrict__ bv,
    ull* __restrict__ bits,
    unsigned short* __restrict__ qs, unsigned short* __restrict__ ks,
    unsigned short* __restrict__ vs,
    unsigned short* __restrict__ qns, unsigned short* __restrict__ kns,
    unsigned short* __restrict__ wo_bf)
{
  __shared__ unsigned short xfrag[32768];   // 64 KB (qkv branch only)
  __shared__ unsigned short stage[4096];
  __shared__ float irn_lds[64];
  const int bx = blockIdx.x;
  const int w = threadIdx.x >> 6, L = threadIdx.x & 63, c = L & 15, g = L >> 4;
  const int t = threadIdx.x;

  if (bx >= 2432) {
    const int i = (bx - 2432) * 256 + t;
    float4 v = reinterpret_cast<const float4*>(wo)[i];
    u16x4 o;
    o[0] = f2bf(v.x); o[1] = f2bf(v.y); o[2] = f2bf(v.z); o[3] = f2bf(v.w);
    reinterpret_cast<u16x4*>(wo_bf)[i] = o;
    return;
  }
  if (bx >= 384) {
    const long long row = (long long)(bx - 384) * 4 + w;
    const float* mp = mask + row * 1024 + 4 * L;
    ull* bout = bits + row * 16;
#pragma unroll
    for (int p = 0; p < 4; ++p) {
      float4 v = *reinterpret_cast<const float4*>(mp + 256 * p);
      ull b0 = __ballot(v.x != 0.f);
      ull b1 = __ballot(v.y != 0.f);
      ull b2 = __ballot(v.z != 0.f);
      ull b3 = __ballot(v.w != 0.f);
      if (L == 0) {
        bout[4 * p + 0] = b0; bout[4 * p + 1] = b1;
        bout[4 * p + 2] = b2; bout[4 * p + 3] = b3;
      }
    }
    return;
  }

  // ---- QKV GEMM ----
  const int m0 = (bx & 127) * 64;
  const int p = bx >> 7;
  const unsigned short* Wf = (p == 0) ? wqf : (p == 1) ? wkf : wvf;
  const float* bias = (p == 0) ? bq : (p == 1) ? bk : bv;

  const float4* xsrc = reinterpret_cast<const float4*>(x + (long long)m0 * 512);
#pragma unroll 4
  for (int pass = 0; pass < 32; ++pass) {
    const int flat = pass * 1024 + t * 4;
    const int row = flat >> 9, k0 = flat & 511;
    float4 v = xsrc[pass * 256 + t];
    u16x4 o;
    o[0] = f2bf(v.x); o[1] = f2bf(v.y); o[2] = f2bf(v.z); o[3] = f2bf(v.w);
    const int off = (row >> 4) * 8192 + (k0 >> 5) * 512 +
                    ((((k0 >> 3) & 3) << 4) + (row & 15)) * 8 + (k0 & 7);
    *reinterpret_cast<u16x4*>(xfrag + off) = o;
  }
  __syncthreads();

  const int b = m0 >> 10;
  const int mloc = m0 & 1023;

  for (int h = 0; h < 8; ++h) {
    f32x4 acc0 = {0.f, 0.f, 0.f, 0.f}, acc1 = acc0, acc2 = acc0, acc3 = acc0;
    const unsigned short* xw = xfrag + w * 8192 + L * 8;
    const unsigned short* wb = Wf + (long long)h * 32768 + L * 8;
#pragma unroll 4
    for (int kk = 0; kk < 16; ++kk) {
      bf8_t a  = *reinterpret_cast<const bf8_t*>(xw + kk * 512);
      const unsigned short* wk8 = wb + kk * 2048;
      bf8_t b0 = *reinterpret_cast<const bf8_t*>(wk8);
      bf8_t b1 = *reinterpret_cast<const bf8_t*>(wk8 + 512);
      bf8_t b2 = *reinterpret_cast<const bf8_t*>(wk8 + 1024);
      bf8_t b3 = *reinterpret_cast<const bf8_t*>(wk8 + 1536);
      acc0 = __builtin_amdgcn_mfma_f32_16x16x32_bf16(a, b0, acc0, 0, 0, 0);
      acc1 = __builtin_amdgcn_mfma_f32_16x16x32_bf16(a, b1, acc1, 0, 0, 0);
      acc2 = __builtin_amdgcn_mfma_f32_16x16x32_bf16(a, b2, acc2, 0, 0, 0);
      acc3 = __builtin_amdgcn_mfma_f32_16x16x32_bf16(a, b3, acc3, 0, 0, 0);
    }
    f32x4 accs[4] = {acc0, acc1, acc2, acc3};
    unsigned short ub[4][4];
    float nacc[4] = {0.f, 0.f, 0.f, 0.f};
#pragma unroll
    for (int tt = 0; tt < 4; ++tt) {
      float bvt = bias[h * 64 + 16 * tt + c];
#pragma unroll
      for (int r = 0; r < 4; ++r) {
        ub[tt][r] = f2bf(accs[tt][r] + bvt);
        float vv = bf2f(ub[tt][r]);
        nacc[r] += vv * vv;
      }
    }
    if (p == 2) {
      const long long vbase = (long long)(b * 8 + h) * 65536 +
                              (long long)((mloc >> 5) + (w >> 1)) * 2048 +
                              (16 * g + c) * 8 + 4 * (w & 1);
#pragma unroll
      for (int tt = 0; tt < 4; ++tt) {
        u16x4 o;
#pragma unroll
        for (int r = 0; r < 4; ++r) o[r] = ub[tt][r];
        *reinterpret_cast<u16x4*>(vs + vbase + tt * 512) = o;
      }
    } else {
      float irn[4];
#pragma unroll
      for (int r = 0; r < 4; ++r) {
#pragma unroll
        for (int off = 1; off < 16; off <<= 1) nacc[r] += __shfl_xor(nacc[r], off, 64);
        irn[r] = rsqrtf(nacc[r]);
      }
      if (c == 0) {
#pragma unroll
        for (int r = 0; r < 4; ++r) irn_lds[16 * w + 4 * g + r] = irn[r];
      }
#pragma unroll
      for (int tt = 0; tt < 4; ++tt) {
        const int half = tt >> 1;
        const int lpart = 16 * ((2 * tt + (c >> 3)) & 3);
#pragma unroll
        for (int r = 0; r < 4; ++r)
          stage[w * 1024 + half * 512 + (lpart + 4 * g + r) * 8 + (c & 7)] = ub[tt][r];
      }
      __syncthreads();
      unsigned short* dst = (p == 0) ? qs : ks;
      unsigned short* nrm = (p == 0) ? qns : kns;
      const long long qsb0 = (long long)(b * 8 + h) * 65536 + (long long)(mloc >> 4) * 1024;
      const long long nsb0 = (long long)b * 524288 + (long long)(mloc >> 4) * 8192 +
                             (long long)(2 * h) * 512;
#pragma unroll
      for (int pass = 0; pass < 2; ++pass) {
        const int Wd = t + 256 * pass;
        const int tile = Wd >> 7, lane = Wd & 63;
        const int il = tile * 16 + (Wd & 15);
        bf8_t v = *reinterpret_cast<const bf8_t*>(stage + Wd * 8);
        float f = irn_lds[il];
        *reinterpret_cast<bf8_t*>(dst + qsb0 + (long long)Wd * 8) = v;
        bf8_t nv;
#pragma unroll
        for (int e = 0; e < 8; ++e)
          nv[e] = (short)f2bf(bf2f((unsigned short)v[e]) * f);
        *reinterpret_cast<bf8_t*>(nrm + nsb0 + (long long)tile * 8192 +
                                  (long long)((Wd >> 6) & 1) * 512 + (long long)lane * 8) = nv;
      }
      __syncthreads();
    }
  }
}

// ---------------- merged: attn (by<64) + loss (by 64..71) — r15 schedule (best) ----------------
__global__ __launch_bounds__(512, 4) void attn_loss_kernel(
    const unsigned short* __restrict__ qs, const unsigned short* __restrict__ ks,
    const ull* __restrict__ bits, const unsigned short* __restrict__ vs,
    const unsigned short* __restrict__ qns, const unsigned short* __restrict__ kns,
    float* __restrict__ attn_out, unsigned short* __restrict__ inter,
    float* __restrict__ partials)
{
  __shared__ unsigned int PO_lds[8 * 1088];   // 34.8 KB union P/O
  __shared__ float redM[8][16], redS[8][16];
  __shared__ float redN[8][16], redD[8][16], redP[8][16];
  const int w = threadIdx.x >> 6, L = threadIdx.x & 63, c = L & 15, g = L >> 4;

  if (blockIdx.y < 64) {
    const int bh = blockIdx.x;                 // fast dim -> XCD locality
    const int i0 = blockIdx.y * 16;
    const int b = bh >> 3, h = bh & 7;
    const int j0 = 128 * w;
    const long long bho = (long long)bh * 65536;

    const unsigned short* qp = qs + bho + (i0 >> 4) * 1024 + L * 8;
    bf8_t qf0 = *reinterpret_cast<const bf8_t*>(qp);
    bf8_t qf1 = *reinterpret_cast<const bf8_t*>(qp + 512);

    const ull* bp = bits + ((long long)b * 1024 + i0 + c) * 16 + 4 * (w >> 1);
    ull mw[4];
    {
      ulonglong2 m01 = *reinterpret_cast<const ulonglong2*>(bp);
      ulonglong2 m23 = *reinterpret_cast<const ulonglong2*>(bp + 2);
      mw[0] = m01.x; mw[1] = m01.y; mw[2] = m23.x; mw[3] = m23.y;
    }
    const int bitbase = 32 * (w & 1) + g;

    f32x4 sc[8];
    const unsigned short* kp = ks + bho + (long long)(8 * w) * 1024 + L * 8;
#pragma unroll
    for (int jt = 0; jt < 8; ++jt) {
      const unsigned short* kt = kp + jt * 1024;
      f32x4 acc = {0.f, 0.f, 0.f, 0.f};
      acc = __builtin_amdgcn_mfma_f32_16x16x32_bf16(*reinterpret_cast<const bf8_t*>(kt), qf0, acc, 0, 0, 0);
      acc = __builtin_amdgcn_mfma_f32_16x16x32_bf16(*reinterpret_cast<const bf8_t*>(kt + 512), qf1, acc, 0, 0, 0);
      sc[jt] = acc;
    }

    // hoist V fragments m=0,1 (8 loads) above the softmax VALU phase
    const unsigned short* vbase = vs + bho + (long long)(16 * w) * 512 + L * 8;
    bf8_t vpre[8];
#pragma unroll
    for (int vv = 0; vv < 8; ++vv) vpre[vv] = *reinterpret_cast<const bf8_t*>(vbase + vv * 512);

    float rmax = -1e30f;
#pragma unroll
    for (int jt = 0; jt < 8; ++jt) {
#pragma unroll
      for (int r = 0; r < 4; ++r) {
        float lg = ((mw[r] >> (bitbase + 4 * jt)) & 1ull) ? sc[jt][r] * 0.125f
                                                          : -2.8782313662425572f;
        sc[jt][r] = lg;
        rmax = fmaxf(rmax, lg);
      }
    }
    rmax = fmaxf(rmax, __shfl_xor(rmax, 16, 64));
    rmax = fmaxf(rmax, __shfl_xor(rmax, 32, 64));
    float rsum = 0.f;
#pragma unroll
    for (int jt = 0; jt < 8; ++jt) {
#pragma unroll
      for (int r = 0; r < 4; ++r) {
        float e = __expf(sc[jt][r] - rmax);
        sc[jt][r] = e;
        rsum += e;
      }
    }
    rsum += __shfl_xor(rsum, 16, 64);
    rsum += __shfl_xor(rsum, 32, 64);
    if (L < 16) { redM[w][L] = rmax; redS[w][L] = rsum; }
    __syncthreads();  // B1
    float M = redM[0][c];
#pragma unroll
    for (int ww = 1; ww < 8; ++ww) M = fmaxf(M, redM[ww][c]);
    float den = 0.f;
#pragma unroll
    for (int ww = 0; ww < 8; ++ww) den += redS[ww][c] * __expf(redM[ww][c] - M);
    const float scale = __expf(rmax - M) / den;

    // scale + pack; stage P rows into my LDS plane
    unsigned int* Pw = PO_lds + w * 1088;
    unsigned int pk[16];
#pragma unroll
    for (int jt = 0; jt < 8; ++jt) {
      f32x4 pv;
#pragma unroll
      for (int r = 0; r < 4; ++r) pv[r] = sc[jt][r] * scale;
      pk[2 * jt]     = pack2(pv[0], pv[1]);
      pk[2 * jt + 1] = pack2(pv[2], pv[3]);
      u32x2 pw2;
      pw2[0] = pk[2 * jt]; pw2[1] = pk[2 * jt + 1];
      *reinterpret_cast<u32x2*>(Pw + c * 68 + 8 * jt + 2 * g) = pw2;
    }

    // issue remaining V loads (m=2,3) before the MFMA burst
    bf8_t vtail[8];
#pragma unroll
    for (int vv = 0; vv < 8; ++vv)
      vtail[vv] = *reinterpret_cast<const bf8_t*>(vbase + (8 + vv) * 512);

    // PV: pure MFMA burst from registers
    f32x4 oacc[4] = {{0.f,0.f,0.f,0.f},{0.f,0.f,0.f,0.f},{0.f,0.f,0.f,0.f},{0.f,0.f,0.f,0.f}};
#pragma unroll
    for (int m = 0; m < 4; ++m) {
      union { unsigned int u[4]; bf8_t v; } af;
#pragma unroll
      for (int q = 0; q < 4; ++q) af.u[q] = pk[4 * m + q];
#pragma unroll
      for (int tt = 0; tt < 4; ++tt) {
        bf8_t vb = (m < 2) ? vpre[4 * m + tt] : vtail[4 * (m - 2) + tt];
        oacc[tt] = __builtin_amdgcn_mfma_f32_16x16x32_bf16(af.v, vb, oacc[tt], 0, 0, 0);
      }
    }

    // coalesced attn store: f32x4, two rows per pass (lanes split), 1 KB/instr
    {
      float* aobase = attn_out + (long long)bh * 1048576 + (long long)i0 * 1024 + j0;
      const int lj = L & 31, lh = L >> 5;
#pragma unroll
      for (int ii = 0; ii < 8; ++ii) {
        const int row = 2 * ii + lh;
        u32x2 u2 = *reinterpret_cast<const u32x2*>(Pw + row * 68 + 2 * lj);
        f32x4 o4;
        o4[0] = bf2f((unsigned short)(u2[0] & 0xffff));
        o4[1] = bf2f((unsigned short)(u2[0] >> 16));
        o4[2] = bf2f((unsigned short)(u2[1] & 0xffff));
        o4[3] = bf2f((unsigned short)(u2[1] >> 16));
        __builtin_nontemporal_store(o4,
            reinterpret_cast<f32x4*>(aobase + (long long)row * 1024 + 4 * lj));
      }
    }

    // O partials into my plane (overwrites P; my P reads are done)
    {
      float* Ow = reinterpret_cast<float*>(PO_lds + w * 1088);
#pragma unroll
      for (int tt = 0; tt < 4; ++tt)
#pragma unroll
        for (int r = 0; r < 4; ++r)
          Ow[(4 * g + r) * 67 + 16 * tt + c] = oacc[tt][r];
    }
    __syncthreads();  // B2

    {
      const int d = threadIdx.x & 63, rw = threadIdx.x >> 6;
#pragma unroll
      for (int ii = 0; ii < 2; ++ii) {
        const int i = rw + 8 * ii;
        float s = 0.f;
#pragma unroll
        for (int ww = 0; ww < 8; ++ww)
          s += reinterpret_cast<const float*>(PO_lds + ww * 1088)[i * 67 + d];
        inter[((long long)b * 1024 + i0 + i) * 512 + h * 64 + d] = f2bf(s);
      }
    }
  } else {
    const int i0 = blockIdx.x * 16;
    const int b = blockIdx.y - 64;
    const long long rowbase = (long long)b * 1024;

    f32x4 acc[8];
#pragma unroll
    for (int jt = 0; jt < 8; ++jt) acc[jt] = f32x4{0.f, 0.f, 0.f, 0.f};
    const unsigned short* qp = qns + (long long)b * 524288 + (long long)(i0 >> 4) * 8192 + L * 8;
    const unsigned short* kp = kns + (long long)b * 524288 + (long long)(8 * w) * 8192 + L * 8;
#pragma unroll 2
    for (int kc = 0; kc < 16; ++kc) {
      bf8_t a = *reinterpret_cast<const bf8_t*>(qp + kc * 512);
#pragma unroll
      for (int jt = 0; jt < 8; ++jt) {
        bf8_t bb = *reinterpret_cast<const bf8_t*>(kp + jt * 8192 + kc * 512);
        acc[jt] = __builtin_amdgcn_mfma_f32_16x16x32_bf16(a, bb, acc[jt], 0, 0, 0);
      }
    }

    const int e = c & 3, csh = c >> 2, half = (w & 1) * 32;
    ull w64[4];
#pragma unroll
    for (int r = 0; r < 4; ++r)
      w64[r] = bits[(rowbase + i0 + 4 * g + r) * 16 + 4 * (w >> 1) + e];

    float num[4] = {0.f, 0.f, 0.f, 0.f}, den[4] = {0.f, 0.f, 0.f, 0.f}, pcv[4];
#pragma unroll
    for (int r = 0; r < 4; ++r)
      pcv[r] = (c < 4) ? (float)__popcll((w64[r] >> half) & 0xFFFFFFFFull) : 0.f;
#pragma unroll
    for (int jt = 0; jt < 8; ++jt) {
#pragma unroll
      for (int r = 0; r < 4; ++r) {
        float ee = __expf(acc[jt][r] * 1.25f);
        den[r] += ee;
        num[r] += ((w64[r] >> (half + 4 * jt + csh)) & 1ull) ? ee : 0.f;
      }
    }
#pragma unroll
    for (int r = 0; r < 4; ++r) {
#pragma unroll
      for (int off = 1; off < 16; off <<= 1) {
        num[r] += __shfl_xor(num[r], off, 64);
        den[r] += __shfl_xor(den[r], off, 64);
        pcv[r] += __shfl_xor(pcv[r], off, 64);
      }
    }
    if (c == 0) {
#pragma unroll
      for (int r = 0; r < 4; ++r) {
        redN[w][4 * g + r] = num[r]; redD[w][4 * g + r] = den[r]; redP[w][4 * g + r] = pcv[r];
      }
    }
    __syncthreads();
    if (w == 0) {
      float cl = 0.f, rg = 0.f;
      if (L < 16) {
        float nm = 0.f, dn = 0.f, pc = 0.f;
#pragma unroll
        for (int ww = 0; ww < 8; ++ww) { nm += redN[ww][L]; dn += redD[ww][L]; pc += redP[ww][L]; }
        cl = __logf(dn) - __logf(nm);
        rg = pc - 1.0f;
      }
#pragma unroll
      for (int off = 1; off < 64; off <<= 1) { cl += __shfl_xor(cl, off, 64); rg += __shfl_xor(rg, off, 64); }
      if (L == 0)
        partials[b * 64 + blockIdx.x] = cl * (1.0f / 8192.0f) + rg * (float)(0.3 / 8380416.0);
    }
  }
}

// ---------------- out-proj GEMM + folded loss reduction (block x==128) ----------------
__global__ __launch_bounds__(256) void outproj_gemm_kernel(
    const unsigned short* __restrict__ A, const unsigned short* __restrict__ W,
    const float* __restrict__ bias, float* __restrict__ out_f32,
    const float* __restrict__ partials, float* __restrict__ loss_out)
{
  if (blockIdx.x == 128) {
    if (blockIdx.y == 0) {
      int t = threadIdx.x;
      float s = partials[t] + partials[t + 256];
#pragma unroll
      for (int off = 1; off < 64; off <<= 1) s += __shfl_xor(s, off, 64);
      __shared__ float red[4];
      if ((t & 63) == 0) red[t >> 6] = s;
      __syncthreads();
      if (t == 0) loss_out[0] = red[0] + red[1] + red[2] + red[3];
    }
    return;
  }
  const int m0 = blockIdx.x * 64;
  const int n0 = blockIdx.y * 64;
  const int w = threadIdx.x >> 6, L = threadIdx.x & 63, c = L & 15, g = L >> 4;
  const unsigned short* arow = A + (long long)(m0 + 16 * w + c) * 512 + 8 * g;
  const unsigned short* wrow = W + (long long)(n0 + c) * 512 + 8 * g;
  f32x4 acc0 = {0.f, 0.f, 0.f, 0.f}, acc1 = acc0, acc2 = acc0, acc3 = acc0;
#pragma unroll 4
  for (int kk = 0; kk < 16; ++kk) {
    bf8_t a  = *reinterpret_cast<const bf8_t*>(arow + 32 * kk);
    bf8_t b0 = *reinterpret_cast<const bf8_t*>(wrow + 32 * kk);
    bf8_t b1 = *reinterpret_cast<const bf8_t*>(wrow + 16 * 512 + 32 * kk);
    bf8_t b2 = *reinterpret_cast<const bf8_t*>(wrow + 32 * 512 + 32 * kk);
    bf8_t b3 = *reinterpret_cast<const bf8_t*>(wrow + 48 * 512 + 32 * kk);
    acc0 = __builtin_amdgcn_mfma_f32_16x16x32_bf16(a, b0, acc0, 0, 0, 0);
    acc1 = __builtin_amdgcn_mfma_f32_16x16x32_bf16(a, b1, acc1, 0, 0, 0);
    acc2 = __builtin_amdgcn_mfma_f32_16x16x32_bf16(a, b2, acc2, 0, 0, 0);
    acc3 = __builtin_amdgcn_mfma_f32_16x16x32_bf16(a, b3, acc3, 0, 0, 0);
  }
  f32x4 accs[4] = {acc0, acc1, acc2, acc3};
#pragma unroll
  for (int tt = 0; tt < 4; ++tt) {
    int n = n0 + 16 * tt + c;
    float bv = bias[n];
#pragma unroll
    for (int r = 0; r < 4; ++r)
      out_f32[(long long)(m0 + 16 * w + 4 * g + r) * 512 + n] = accs[tt][r] + bv;
  }
}

extern "C" void kernel_launch(void* const* d_in, const int* in_sizes, int n_in,
                              void* d_out, int out_size, void* d_ws, size_t ws_size,
                              hipStream_t stream)
{
  const float* x    = (const float*)d_in[0];
  const float* mask = (const float*)d_in[1];
  const float* wq = (const float*)d_in[2]; const float* bq = (const float*)d_in[3];
  const float* wk = (const float*)d_in[4]; const float* bk = (const float*)d_in[5];
  const float* wv = (const float*)d_in[6]; const float* bv = (const float*)d_in[7];
  const float* wo = (const float*)d_in[8]; const float* bo = (const float*)d_in[9];

  unsigned short* inter = (unsigned short*)d_ws;
  unsigned short* qs    = inter + 4194304;
  unsigned short* ks    = qs + 4194304;
  unsigned short* vsb   = ks + 4194304;
  unsigned short* qns   = vsb + 4194304;
  unsigned short* kns   = qns + 4194304;
  unsigned short* wqf   = kns + 4194304;       // 262144 each
  unsigned short* wkf   = wqf + 262144;
  unsigned short* wvf   = wkf + 262144;
  unsigned short* wo_bf = wvf + 262144;
  ull* bits    = (ull*)(wo_bf + 262144);        // 1 MB
  float* parts = (float*)(bits + 131072);       // 512 f32

  float* out_f  = (float*)d_out;
  float* attn_o = out_f + 4194304;
  float* loss_o = attn_o + 67108864;

  prep_w_kernel<<<768, 256, 0, stream>>>(wq, wk, wv, wqf, wkf, wvf);

  mask_qkv_kernel<<<2688, 256, 0, stream>>>(
      mask, x, wo, wqf, wkf, wvf, bq, bk, bv,
      bits, qs, ks, vsb, qns, kns, wo_bf);

  attn_loss_kernel<<<dim3(64, 72), 512, 0, stream>>>(
      qs, ks, bits, vsb, qns, kns, attn_o, inter, parts);

  outproj_gemm_kernel<<<dim3(129, 8), 256, 0, stream>>>(
      inter, wo_bf, bo, out_f, parts, loss_o);
}